// Round 9
// baseline (24.469 us; speedup 1.0000x reference)
//
#include <hip/hip_runtime.h>
#include <hip/hip_bf16.h>

#define IPS 704          // INPUTS_PER_SQUARE
#define OPS 16           // OUTPUTS_PER_SQUARE
#define NSQ 64           // NUM_SQUARES
#define MAXA 32          // MAX_ACTIVE
#define ROW_OUT 1024     // NSQ * OPS
#define SPB 4            // samples per group
#define GROUPS 4         // groups per block (software pipeline depth)
#define NPAIR (SPB * MAXA)    // 128 (sample,feature) pairs per group
#define SGRP (SPB * GROUPS)   // 16 samples per block

typedef float f32x4 __attribute__((ext_vector_type(4)));

__global__ __launch_bounds__(256) void ft_slice_kernel(
    const int* __restrict__ fidx,
    const float* __restrict__ fval,
    const float* __restrict__ weight,
    float* __restrict__ out)
{
    const int base = blockIdx.x * SGRP;   // first sample of this block
    const int t    = threadIdx.x;

    __shared__ int      s_idx[2][NPAIR];             // 1 KB, double-buffered
    __shared__ float    s_val[2][NPAIR];             // 1 KB, double-buffered
    __shared__ unsigned s_mask[GROUPS][SPB * NSQ];   // 4 KB, one buffer per group
    __shared__ float    s_w[NPAIR * OPS];            // 8 KB, barrier-protected

    const int my_sq = t >> 2;    // square owned in compute phase
    const int my_ch = t & 3;     // float4 chunk owned

    // Zero ALL group mask buffers once (1024 words / 256 threads).
    #pragma unroll
    for (int k = 0; k < GROUPS; ++k)
        (&s_mask[0][0])[t + 256 * k] = 0u;

    auto ld = [&](int g, int& idx, float& v) {
        idx = 0; v = 0.0f;
        if (t < NPAIR) {
            const size_t off = (size_t)(base + g * SPB) * MAXA + t;
            idx = __builtin_nontemporal_load(fidx + off);
            v   = __builtin_nontemporal_load(fval + off);
            if (idx < 0) { idx = 0; v = 0.0f; }   // empty slot
        }
    };
    auto stage = [&](int g, int idx, float v) {
        if (t < NPAIR) {
            const int buf = g & 1;
            s_idx[buf][t] = idx;
            s_val[buf][t] = v;
            const int sq = idx / IPS;             // magic-mul div by const
            atomicOr(&s_mask[g][(t >> 5) * NSQ + sq], 1u << (t & 31));
        }
    };
    auto gather = [&](int g) {
        const int buf = g & 1;
        #pragma unroll
        for (int c = 0; c < NPAIR / 64; ++c) {    // 2 rows per thread
            const int pair = (t >> 2) + 64 * c;
            const int ridx = s_idx[buf][pair];    // broadcast within lane-quad
            const f32x4 w = *reinterpret_cast<const f32x4*>(
                weight + (size_t)ridx * OPS + my_ch * 4);
            *reinterpret_cast<f32x4*>(            // chunk-XOR swizzle
                &s_w[pair * OPS + ((my_ch ^ (pair & 3)) << 2)]) = w;
        }
    };
    auto compute_store = [&](int g) {
        const int buf = g & 1;
        #pragma unroll
        for (int s = 0; s < SPB; ++s) {
            f32x4 acc = (f32x4)(0.0f);
            unsigned m = s_mask[g][s * NSQ + my_sq];
            while (m) {
                const int f = __builtin_ctz(m);
                m &= m - 1;
                const int pair = s * MAXA + f;
                const float vv = s_val[buf][pair];
                const f32x4 w = *reinterpret_cast<const f32x4*>(
                    &s_w[pair * OPS + ((my_ch ^ (pair & 3)) << 2)]);
                acc += vv * w;
            }
            // through-L2 store: fire-and-forget, drains during next group
            *reinterpret_cast<f32x4*>(
                out + (size_t)(base + g * SPB + s) * ROW_OUT + t * 4) = acc;
        }
    };

    // ---- software pipeline across groups ----
    int idx; float v;
    ld(0, idx, v);
    __syncthreads();             // mask zeroing complete
    stage(0, idx, v);
    __syncthreads();             // s_idx/s_mask(0) visible
    gather(0);
    __syncthreads();             // s_w(0) ready

    #pragma unroll
    for (int g = 1; g < GROUPS; ++g) {
        ld(g, idx, v);           // input loads overlap compute of g-1
        compute_store(g - 1);    // reads s_w; stores stream out
        stage(g, idx, v);        // writes buffers not read this region
        __syncthreads();         // all waves done reading s_w(g-1)
        gather(g);               // overwrite s_w
        __syncthreads();         // s_w(g) ready
    }
    compute_store(GROUPS - 1);
}

extern "C" void kernel_launch(void* const* d_in, const int* in_sizes, int n_in,
                              void* d_out, int out_size, void* d_ws, size_t ws_size,
                              hipStream_t stream)
{
    const int*   fidx   = (const int*)d_in[0];    // (16384, 32) int32
    const float* fval   = (const float*)d_in[1];  // (16384, 32) f32
    const float* weight = (const float*)d_in[2];  // (45056, 16) f32
    float*       out    = (float*)d_out;          // (16384, 1024) f32

    const int batch = in_sizes[0] / MAXA;         // 16384
    ft_slice_kernel<<<batch / SGRP, 256, 0, stream>>>(fidx, fval, weight, out);
}

// Round 10
// 20.490 us; speedup vs baseline: 1.1942x; 1.1942x over previous
//
#include <hip/hip_runtime.h>
#include <hip/hip_bf16.h>

#define IPS 704          // INPUTS_PER_SQUARE
#define OPS 16           // OUTPUTS_PER_SQUARE
#define NSQ 64           // NUM_SQUARES
#define MAXA 32          // MAX_ACTIVE
#define ROW_OUT 1024     // NSQ * OPS
#define SPB 8            // samples per block
#define NPAIR (SPB * MAXA)   // 256 (sample,feature) pairs per block

typedef float f32x4 __attribute__((ext_vector_type(4)));

__global__ __launch_bounds__(256) void ft_slice_kernel(
    const int* __restrict__ fidx,
    const float* __restrict__ fval,
    const float* __restrict__ weight,
    float* __restrict__ out)
{
    const int b0 = blockIdx.x * SPB;      // first sample of this block
    const int t  = threadIdx.x;

    __shared__ int      s_pair[NPAIR * 2];   // 2 KB: {idx, val_bits} interleaved
    __shared__ unsigned s_maskT[NSQ * SPB];  // 2 KB: [square][sample] transposed

    // Phase 0: NT input loads; zero masks; stage packed (idx,val) pairs.
    int   idx = __builtin_nontemporal_load(fidx + (size_t)b0 * MAXA + t);
    float v   = __builtin_nontemporal_load(fval + (size_t)b0 * MAXA + t);
    if (idx < 0) { idx = 0; v = 0.0f; }   // empty slot -> zero contribution
    s_maskT[t]       = 0u;
    s_maskT[t + 256] = 0u;
    reinterpret_cast<int2*>(s_pair)[t] = make_int2(idx, __float_as_int(v));
    const int sq = idx / IPS;             // magic-mul div by const
    __syncthreads();

    // Phase 1: build transposed per-(square,sample) bitmasks.
    atomicOr(&s_maskT[sq * SPB + (t >> 5)], 1u << (t & 31));
    __syncthreads();

    // Phase 2: thread t owns square t>>2, float4 chunk t&3, for all SPB
    // samples. Direct global gathers (L2-hot weight), 4-slot static unroll
    // per sample for MLP; rare popcount>4 handled by residual loop.
    const int my_sq = t >> 2;
    const int my_ch = t & 3;

    // all 8 masks in two b128 reads (transposed layout, 32B-aligned)
    const uint4 mlo = *reinterpret_cast<const uint4*>(&s_maskT[my_sq * SPB]);
    const uint4 mhi = *reinterpret_cast<const uint4*>(&s_maskT[my_sq * SPB + 4]);
    unsigned ms[SPB] = {mlo.x, mlo.y, mlo.z, mlo.w, mhi.x, mhi.y, mhi.z, mhi.w};

    #pragma unroll
    for (int ss = 0; ss < SPB; ++ss) {
        unsigned m = ms[ss];
        f32x4 acc = (f32x4)(0.0f);
        #pragma unroll
        for (int k = 0; k < 4; ++k) {
            if (m) {
                const int ff = __builtin_ctz(m);
                m &= m - 1;
                const int2 p = reinterpret_cast<const int2*>(s_pair)[ss * MAXA + ff];
                const f32x4 w = *reinterpret_cast<const f32x4*>(
                    weight + (size_t)p.x * OPS + my_ch * 4);
                acc += __int_as_float(p.y) * w;
            }
        }
        while (m) {   // overflow: >4 features on one (sample,square) — rare
            const int ff = __builtin_ctz(m);
            m &= m - 1;
            const int2 p = reinterpret_cast<const int2*>(s_pair)[ss * MAXA + ff];
            const f32x4 w = *reinterpret_cast<const f32x4*>(
                weight + (size_t)p.x * OPS + my_ch * 4);
            acc += __int_as_float(p.y) * w;
        }
        // through-L2 coalesced store, interleaved per sample
        *reinterpret_cast<f32x4*>(out + (size_t)(b0 + ss) * ROW_OUT + t * 4) = acc;
    }
}

extern "C" void kernel_launch(void* const* d_in, const int* in_sizes, int n_in,
                              void* d_out, int out_size, void* d_ws, size_t ws_size,
                              hipStream_t stream)
{
    const int*   fidx   = (const int*)d_in[0];    // (16384, 32) int32
    const float* fval   = (const float*)d_in[1];  // (16384, 32) f32
    const float* weight = (const float*)d_in[2];  // (45056, 16) f32
    float*       out    = (float*)d_out;          // (16384, 1024) f32

    const int batch = in_sizes[0] / MAXA;         // 16384
    ft_slice_kernel<<<batch / SPB, 256, 0, stream>>>(fidx, fval, weight, out);
}

// Round 11
// 20.438 us; speedup vs baseline: 1.1972x; 1.0025x over previous
//
#include <hip/hip_runtime.h>
#include <hip/hip_bf16.h>

#define IPS 704          // INPUTS_PER_SQUARE
#define OPS 16           // OUTPUTS_PER_SQUARE
#define NSQ 64           // NUM_SQUARES
#define MAXA 32          // MAX_ACTIVE
#define ROW_OUT 1024     // NSQ * OPS
#define WPB 4            // waves per block
#define SPW 2            // samples per wave

typedef float f32x4 __attribute__((ext_vector_type(4)));

// Fully wave-autonomous: no __syncthreads anywhere. Each wave processes
// SPW samples with a private LDS slice; waves drift apart so the store
// stream is continuous instead of phase-locked bursts.
__global__ __launch_bounds__(256) void ft_slice_kernel(
    const int* __restrict__ fidx,
    const float* __restrict__ fval,
    const float* __restrict__ weight,
    float* __restrict__ out)
{
    const int t    = threadIdx.x;
    const int w    = t >> 6;         // wave within block
    const int lane = t & 63;
    const int wg   = blockIdx.x * WPB + w;   // global wave id
    const int b0   = wg * SPW;               // first sample of this wave

    __shared__ int2     s_pair[WPB][SPW][MAXA];  // 2 KB: {idx, val_bits}
    __shared__ unsigned s_mask[WPB][SPW][NSQ];   // 2 KB: per-(sample,square) mask

    // Load BOTH samples' inputs in one coalesced 512B wave-read:
    // lanes 0-31 -> sample A, lanes 32-63 -> sample B.
    const int half = lane >> 5;
    const int f    = lane & 31;
    const size_t off = (size_t)(b0 + half) * MAXA + f;
    int   idx = __builtin_nontemporal_load(fidx + off);
    float v   = __builtin_nontemporal_load(fval + off);
    if (idx < 0) { idx = 0; v = 0.0f; }   // empty slot -> zero contribution
    const int sq = idx / IPS;             // magic-mul div by const

    // Wave-private LDS: DS ops from one wave complete in order, so
    // zero -> stage -> atomicOr needs no barrier; only the read-back
    // below needs an explicit lgkmcnt drain.
    s_mask[w][0][lane] = 0u;              // 64 lanes x 2 words = both masks
    s_mask[w][1][lane] = 0u;
    s_pair[w][half][f] = make_int2(idx, __float_as_int(v));
    atomicOr(&s_mask[w][half][sq], 1u << f);

    asm volatile("s_waitcnt lgkmcnt(0)" ::: "memory");
    __builtin_amdgcn_sched_barrier(0);    // rule #18: pin reads after the wait

    // Lane l, chunk c owns output floats [c*256 + l*4, +4):
    //   square = c*16 + (l>>2), weight chunk = l&3.
    const int qrow = lane >> 2;
    const int ch   = lane & 3;
    const float* wbase = weight + ch * 4;

    #pragma unroll
    for (int s = 0; s < SPW; ++s) {
        #pragma unroll
        for (int c = 0; c < 4; ++c) {
            unsigned m = s_mask[w][s][c * 16 + qrow];
            f32x4 acc = (f32x4)(0.0f);
            while (m) {                   // avg ~0.5 hits/lane, exec-masked
                const int ff = __builtin_ctz(m);
                m &= m - 1;
                const int2 p = s_pair[w][s][ff];
                const f32x4 wv = *reinterpret_cast<const f32x4*>(
                    wbase + (size_t)p.x * OPS);
                acc += __int_as_float(p.y) * wv;
            }
            // contiguous 1KB wave-store (64 lanes x 16B, stride 16B)
            *reinterpret_cast<f32x4*>(
                out + (size_t)(b0 + s) * ROW_OUT + c * 256 + lane * 4) = acc;
        }
    }
}

extern "C" void kernel_launch(void* const* d_in, const int* in_sizes, int n_in,
                              void* d_out, int out_size, void* d_ws, size_t ws_size,
                              hipStream_t stream)
{
    const int*   fidx   = (const int*)d_in[0];    // (16384, 32) int32
    const float* fval   = (const float*)d_in[1];  // (16384, 32) f32
    const float* weight = (const float*)d_in[2];  // (45056, 16) f32
    float*       out    = (float*)d_out;          // (16384, 1024) f32

    const int batch = in_sizes[0] / MAXA;         // 16384
    ft_slice_kernel<<<batch / (WPB * SPW), 256, 0, stream>>>(fidx, fval, weight, out);
}

// Round 12
// 19.743 us; speedup vs baseline: 1.2394x; 1.0352x over previous
//
#include <hip/hip_runtime.h>
#include <hip/hip_bf16.h>

#define IPS 704          // INPUTS_PER_SQUARE
#define OPS 16           // OUTPUTS_PER_SQUARE
#define NSQ 64           // NUM_SQUARES
#define MAXA 32          // MAX_ACTIVE
#define ROW_OUT 1024     // NSQ * OPS
#define SPB 16           // samples per block (monolithic, amortize barriers/ramp)
#define NPAIR (SPB * MAXA)   // 512 (sample,feature) pairs per block

typedef float f32x4 __attribute__((ext_vector_type(4)));

__global__ __launch_bounds__(256) void ft_slice_kernel(
    const int* __restrict__ fidx,
    const float* __restrict__ fval,
    const float* __restrict__ weight,
    float* __restrict__ out)
{
    const int b0 = blockIdx.x * SPB;      // first sample of this block
    const int t  = threadIdx.x;

    __shared__ int      s_idx[NPAIR];          // 2 KB
    __shared__ float    s_val[NPAIR];          // 2 KB
    __shared__ unsigned s_mask[SPB * NSQ];     // 4 KB  per-(sample,square) bitmask
    __shared__ float    s_w[NPAIR * OPS];      // 32 KB weight rows, chunk-XOR-swizzled

    // Phase 0: NT input loads (read-once); zero masks; stage idx/val.
    #pragma unroll
    for (int k = 0; k < SPB * NSQ / 256; ++k)
        s_mask[t + 256 * k] = 0u;

    int   idxr[NPAIR / 256];
    float valr[NPAIR / 256];
    #pragma unroll
    for (int k = 0; k < NPAIR / 256; ++k) {
        const int p = t + 256 * k;
        int   idx = __builtin_nontemporal_load(fidx + (size_t)b0 * MAXA + p);
        float v   = __builtin_nontemporal_load(fval + (size_t)b0 * MAXA + p);
        if (idx < 0) { idx = 0; v = 0.0f; }   // empty slot -> zero contribution
        idxr[k] = idx; valr[k] = v;
        s_idx[p] = idx;
        s_val[p] = v;
    }
    __syncthreads();

    // Phase 1a: build per-(sample,square) feature bitmasks.
    #pragma unroll
    for (int k = 0; k < NPAIR / 256; ++k) {
        const int p  = t + 256 * k;
        const int sq = idxr[k] / IPS;          // magic-mul div by const
        atomicOr(&s_mask[(p >> 5) * NSQ + sq], 1u << (p & 31));
    }

    // Phase 1b: prefetch ALL 512 weight rows into LDS with max MLP.
    // 4 lanes per row, each loads one float4 chunk; 8 rows per thread.
    const int my_ch = t & 3;
    #pragma unroll
    for (int c = 0; c < NPAIR / 64; ++c) {
        const int pair = (t >> 2) + 64 * c;
        const int ridx = s_idx[pair];                 // broadcast within lane-quad
        const f32x4 w = *reinterpret_cast<const f32x4*>(
            weight + (size_t)ridx * OPS + my_ch * 4);
        // XOR-swizzle chunk position to spread phase-2 banks
        *reinterpret_cast<f32x4*>(
            &s_w[pair * OPS + ((my_ch ^ (pair & 3)) << 2)]) = w;
    }
    __syncthreads();

    // Phase 2: thread t owns square t>>2, float4 chunk t&3, for all SPB
    // samples. LDS-only divergent loop (avg popcount 0.5/square).
    const int my_sq = t >> 2;

    #pragma unroll
    for (int s = 0; s < SPB; ++s) {
        f32x4 acc = (f32x4)(0.0f);
        unsigned m = s_mask[s * NSQ + my_sq];
        while (m) {
            const int f = __builtin_ctz(m);
            m &= m - 1;
            const int pair = s * MAXA + f;
            const float vv = s_val[pair];
            const f32x4 w = *reinterpret_cast<const f32x4*>(
                &s_w[pair * OPS + ((my_ch ^ (pair & 3)) << 2)]);
            acc += vv * w;
        }
        // through-L2 coalesced store, interleaved per sample
        *reinterpret_cast<f32x4*>(
            out + (size_t)(b0 + s) * ROW_OUT + t * 4) = acc;
    }
}

extern "C" void kernel_launch(void* const* d_in, const int* in_sizes, int n_in,
                              void* d_out, int out_size, void* d_ws, size_t ws_size,
                              hipStream_t stream)
{
    const int*   fidx   = (const int*)d_in[0];    // (16384, 32) int32
    const float* fval   = (const float*)d_in[1];  // (16384, 32) f32
    const float* weight = (const float*)d_in[2];  // (45056, 16) f32
    float*       out    = (float*)d_out;          // (16384, 1024) f32

    const int batch = in_sizes[0] / MAXA;         // 16384
    ft_slice_kernel<<<batch / SPB, 256, 0, stream>>>(fidx, fval, weight, out);
}